// Round 5
// baseline (193.966 us; speedup 1.0000x reference)
//
#include <hip/hip_runtime.h>
#include <math.h>

#define TB 2048
#define CC 1024
#define NH 16
#define HD 64

typedef __bf16 bf16x8 __attribute__((ext_vector_type(8)));
typedef __bf16 bf16x4 __attribute__((ext_vector_type(4)));
typedef float  f32x4  __attribute__((ext_vector_type(4)));

__device__ inline float exp2fast(float x) { return __builtin_amdgcn_exp2f(x); }

// async global->LDS, 16B per lane; LDS dest = wave-uniform base + lane*16
__device__ __forceinline__ void gl_lds16(const __bf16* g, __bf16* l) {
    __builtin_amdgcn_global_load_lds(
        (const __attribute__((address_space(1))) void*)g,
        (__attribute__((address_space(3))) void*)l, 16, 0, 0);
}

// ---------------------------------------------------------------------------
// fp32 -> bf16 straight convert (hidden_states)
// ---------------------------------------------------------------------------
__global__ __launch_bounds__(256)
void cvt_kernel(const float* __restrict__ src, __bf16* __restrict__ dst) {
    int i = (blockIdx.x * 256 + threadIdx.x) * 4;
    f32x4 v = *(const f32x4*)&src[i];
    bf16x4 o;
    o.x = (__bf16)v.x; o.y = (__bf16)v.y; o.z = (__bf16)v.z; o.w = (__bf16)v.w;
    *(bf16x4*)&dst[i] = o;
}

// ---------------------------------------------------------------------------
// fp32 [K][N] -> bf16 [N][K] tiled transpose (weights, one-time)
// ---------------------------------------------------------------------------
__global__ __launch_bounds__(256)
void tpose_kernel(const float* __restrict__ src, __bf16* __restrict__ dst,
                  int K, int N) {
    __shared__ __bf16 L[64][68];
    const int tid = threadIdx.x;
    const int n0 = blockIdx.x * 64, k0 = blockIdx.y * 64;
    #pragma unroll
    for (int i = 0; i < 4; i++) {
        int id = tid + i * 256;
        int r = id >> 4, c = (id & 15) * 4;
        f32x4 v = *(const f32x4*)&src[(size_t)(k0 + r) * N + n0 + c];
        bf16x4 o;
        o.x = (__bf16)v.x; o.y = (__bf16)v.y; o.z = (__bf16)v.z; o.w = (__bf16)v.w;
        *(bf16x4*)&L[r][c] = o;
    }
    __syncthreads();
    #pragma unroll
    for (int i = 0; i < 4; i++) {
        int id = tid + i * 256;
        int nr = id >> 4, kc = (id & 15) * 4;
        bf16x4 o;
        o.x = L[kc + 0][nr]; o.y = L[kc + 1][nr];
        o.z = L[kc + 2][nr]; o.w = L[kc + 3][nr];
        *(bf16x4*)&dst[(size_t)(n0 + nr) * K + k0 + kc] = o;
    }
}

// ---------------------------------------------------------------------------
// m97-style bf16 GEMM, B pre-transposed [N][K]. Tile 128 x BN, BK=32.
// XOR-swizzled LDS (sw(row)=(row+(row>>2))&3 on 8-elem segments) -> 2-way
// max bank aliasing on the b128 frag reads (free). MFMA operands swapped
// (acc = C^T): each thread owns 4 consecutive n -> vectorized epilogue.
// MODE 0: bias+split+fake-quant -> bf16 q/k/v [B,H,T,D]; Q pre-scaled by
// 0.125*log2(e). MODE 1: bias -> fp32 row-major.
// ---------------------------------------------------------------------------
template<int BN, int MODE>
__global__ __launch_bounds__(256)
void gemm_bt(const __bf16* __restrict__ A, const __bf16* __restrict__ Bt,
             const float* __restrict__ bias,
             __bf16* __restrict__ o0, __bf16* __restrict__ o1,
             __bf16* __restrict__ o2, float* __restrict__ of,
             int M, int N, int K,
             const float* __restrict__ scp, const float* __restrict__ zpp)
{
    constexpr int NT = BN / 32;
    __shared__ __bf16 Asm[128][32];
    __shared__ __bf16 Bsm[BN][32];

    const int tid  = threadIdx.x;
    const int m0   = blockIdx.y * 128;
    const int n0   = blockIdx.x * BN;
    const int w    = tid >> 6, lane = tid & 63;
    const int wm   = (w & 1) * 64, wn = (w >> 1) * (BN / 2);
    const int r16  = lane & 15, quad = lane >> 4;
    // staging: 4 lanes/row; swizzle which 16B segment each lane fetches
    const int srow = lane >> 2;
    const int ssw  = (srow + (srow >> 2)) & 3;
    const int scol = ((lane & 3) ^ ssw) * 8;
    // frag reads: loop-invariant swizzled column
    const int rsw  = (r16 + (r16 >> 2)) & 3;
    const int rcol = (quad ^ rsw) * 8;

    f32x4 acc[NT][4];
    #pragma unroll
    for (int i = 0; i < NT; i++)
        #pragma unroll
        for (int j = 0; j < 4; j++) acc[i][j] = 0.f;

    for (int k0 = 0; k0 < K; k0 += 32) {
        #pragma unroll
        for (int p = 0; p < 2; p++)
            gl_lds16(&A[(size_t)(m0 + p * 64 + w * 16 + srow) * K + k0 + scol],
                     &Asm[p * 64 + w * 16][0]);
        #pragma unroll
        for (int p = 0; p < BN / 64; p++)
            gl_lds16(&Bt[(size_t)(n0 + p * 64 + w * 16 + srow) * K + k0 + scol],
                     &Bsm[p * 64 + w * 16][0]);
        __syncthreads();

        bf16x8 af[4], bfr[NT];
        #pragma unroll
        for (int mt = 0; mt < 4; mt++)
            af[mt] = *(const bf16x8*)&Asm[wm + mt * 16 + r16][rcol];
        #pragma unroll
        for (int nt = 0; nt < NT; nt++)
            bfr[nt] = *(const bf16x8*)&Bsm[wn + nt * 16 + r16][rcol];
        // D = Btile . Atile^T  (C^T): rows = n, cols = m
        #pragma unroll
        for (int nt = 0; nt < NT; nt++)
            #pragma unroll
            for (int mt = 0; mt < 4; mt++)
                acc[nt][mt] = __builtin_amdgcn_mfma_f32_16x16x32_bf16(
                    bfr[nt], af[mt], acc[nt][mt], 0, 0, 0);
        __syncthreads();
    }

    const float sc = scp[0];
    const float zp = zpp[0];

    #pragma unroll
    for (int nt = 0; nt < NT; nt++) {
        #pragma unroll
        for (int mt = 0; mt < 4; mt++) {
            int gm = m0 + wm + mt * 16 + r16;          // C row (col of D)
            int gn = n0 + wn + nt * 16 + quad * 4;      // C col base (row of D)
            f32x4 val = acc[nt][mt] + *(const f32x4*)&bias[gn];
            if (MODE == 1) {
                *(f32x4*)&of[(size_t)gm * N + gn] = val;
            } else {
                int part = gn >> 10;
                int idx  = gn & 1023;
                int h = idx >> 6, d = idx & 63;
                int b = gm >> 11, t = gm & 2047;
                size_t off = (((size_t)(b * NH + h)) * TB + t) * HD + d;
                bf16x4 st;
                if (part == 0) {
                    #pragma unroll
                    for (int r = 0; r < 4; r++)
                        st[r] = (__bf16)(val[r] * 0.18033688f);  // 0.125*log2e
                    *(bf16x4*)&o0[off] = st;
                } else {
                    #pragma unroll
                    for (int r = 0; r < 4; r++) {
                        float qv = val[r] / sc + zp;
                        qv = rintf(qv);                 // half-to-even
                        qv = fminf(fmaxf(qv, 0.f), 255.f);
                        st[r] = (__bf16)((qv - zp) * sc);
                    }
                    if (part == 1) *(bf16x4*)&o1[off] = st;
                    else           *(bf16x4*)&o2[off] = st;
                }
            }
        }
    }
}

// ---------------------------------------------------------------------------
// Transposed-S MFMA flash attention (unchanged from round 4).
// ---------------------------------------------------------------------------
__global__ __launch_bounds__(256, 4)
void attn_mfma(const __bf16* __restrict__ Q, const __bf16* __restrict__ Kg,
               const __bf16* __restrict__ Vg, __bf16* __restrict__ O)
{
    __shared__ alignas(16) __bf16 Ksm[64][72];   // [key][d]
    __shared__ alignas(16) __bf16 Vsm[64][72];   // [d][key]

    const int tid  = threadIdx.x;
    const int qt   = 31 - (blockIdx.x >> 5);     // heavy q-tiles first
    const int bh   = blockIdx.x & 31;
    const int q0   = qt * 64;
    const int w    = tid >> 6, lane = tid & 63;
    const int l15  = lane & 15, quad = lane >> 4;
    const int b    = bh >> 4, h = bh & 15;

    const int krow = tid >> 3;            // 0..31
    const int kseg = (tid & 7) * 8;
    const int vkey = tid & 63;
    const int vc   = tid >> 6;            // 0..3

    const __bf16* Kbh = Kg + (size_t)bh * TB * HD;
    const __bf16* Vbh = Vg + (size_t)bh * TB * HD;

    const __bf16* Qrow = Q + ((size_t)bh * TB + q0 + w * 16 + l15) * HD;
    bf16x8 qf0 = *(const bf16x8*)&Qrow[quad * 8];
    bf16x8 qf1 = *(const bf16x8*)&Qrow[32 + quad * 8];

    const int rbase = (l15 >> 2) * 8 + (l15 & 3);

    bf16x8 af_l;
    {
        __bf16 v = (l15 == 0) ? (__bf16)1.0f : (__bf16)0.0f;
        #pragma unroll
        for (int j = 0; j < 8; j++) af_l[j] = v;
    }

    f32x4 acc_o[4], acc_l;
    #pragma unroll
    for (int nt = 0; nt < 4; nt++) acc_o[nt] = 0.f;
    acc_l = 0.f;
    float mrun = -3.0e38f;

    bf16x8 kpre0 = *(const bf16x8*)&Kbh[(size_t)krow * HD + kseg];
    bf16x8 kpre1 = *(const bf16x8*)&Kbh[(size_t)(32 + krow) * HD + kseg];
    bf16x8 vpre0 = *(const bf16x8*)&Vbh[(size_t)vkey * HD + vc * 8];
    bf16x8 vpre1 = *(const bf16x8*)&Vbh[(size_t)vkey * HD + (4 + vc) * 8];

    for (int kt = 0; kt <= qt; kt++) {
        __syncthreads();
        *(bf16x8*)&Ksm[krow][kseg]      = kpre0;
        *(bf16x8*)&Ksm[32 + krow][kseg] = kpre1;
        #pragma unroll
        for (int j = 0; j < 8; j++) {
            Vsm[vc * 8 + j][vkey]      = vpre0[j];
            Vsm[32 + vc * 8 + j][vkey] = vpre1[j];
        }
        __syncthreads();

        if (kt < qt) {
            const __bf16* Kn = Kbh + (size_t)(kt + 1) * 64 * HD;
            const __bf16* Vn = Vbh + (size_t)(kt + 1) * 64 * HD;
            kpre0 = *(const bf16x8*)&Kn[(size_t)krow * HD + kseg];
            kpre1 = *(const bf16x8*)&Kn[(size_t)(32 + krow) * HD + kseg];
            vpre0 = *(const bf16x8*)&Vn[(size_t)vkey * HD + vc * 8];
            vpre1 = *(const bf16x8*)&Vn[(size_t)vkey * HD + (4 + vc) * 8];
        }

        const bool diag = (kt == qt);

        f32x4 s[4];
        #pragma unroll
        for (int nt = 0; nt < 4; nt++) s[nt] = 0.f;
        #pragma unroll
        for (int nt = 0; nt < 4; nt++) {
            if (diag && (nt & 1) && w < 2) continue;   // keys>=32 all masked
            int row = rbase + (nt & 1) * 32 + ((nt >> 1) << 2);
            bf16x8 kf0 = *(const bf16x8*)&Ksm[row][quad * 8];
            bf16x8 kf1 = *(const bf16x8*)&Ksm[row][32 + quad * 8];
            s[nt] = __builtin_amdgcn_mfma_f32_16x16x32_bf16(kf0, qf0, s[nt], 0, 0, 0);
            s[nt] = __builtin_amdgcn_mfma_f32_16x16x32_bf16(kf1, qf1, s[nt], 0, 0, 0);
        }

        if (diag) {
            #pragma unroll
            for (int nt = 0; nt < 4; nt++) {
                int koff = (nt & 1) * 32 + ((nt >> 1) << 2) + quad * 8;
                #pragma unroll
                for (int r = 0; r < 4; r++)
                    if (koff + r > w * 16 + l15) s[nt][r] = -3.0e38f;
            }
        }

        float mx = s[0][0];
        #pragma unroll
        for (int nt = 0; nt < 4; nt++)
            #pragma unroll
            for (int r = 0; r < 4; r++) mx = fmaxf(mx, s[nt][r]);
        mx = fmaxf(mx, __shfl_xor(mx, 16));
        mx = fmaxf(mx, __shfl_xor(mx, 32));

        float mnew  = fmaxf(mrun, mx);
        float alpha = exp2fast(mrun - mnew);
        mrun = mnew;
        #pragma unroll
        for (int nt = 0; nt < 4; nt++)
            #pragma unroll
            for (int r = 0; r < 4; r++) acc_o[nt][r] *= alpha;
        acc_l[0] *= alpha;

        float p[4][4];
        #pragma unroll
        for (int nt = 0; nt < 4; nt++)
            #pragma unroll
            for (int r = 0; r < 4; r++) p[nt][r] = exp2fast(s[nt][r] - mnew);

        bf16x8 pf0, pf1;
        #pragma unroll
        for (int j = 0; j < 4; j++) {
            pf0[j]     = (__bf16)p[0][j];
            pf0[4 + j] = (__bf16)p[2][j];
            pf1[j]     = (__bf16)p[1][j];
            pf1[4 + j] = (__bf16)p[3][j];
        }

        acc_l = __builtin_amdgcn_mfma_f32_16x16x32_bf16(af_l, pf0, acc_l, 0, 0, 0);
        acc_l = __builtin_amdgcn_mfma_f32_16x16x32_bf16(af_l, pf1, acc_l, 0, 0, 0);

        #pragma unroll
        for (int nt = 0; nt < 4; nt++) {
            bf16x8 vf0 = *(const bf16x8*)&Vsm[nt * 16 + l15][quad * 8];
            bf16x8 vf1 = *(const bf16x8*)&Vsm[nt * 16 + l15][32 + quad * 8];
            acc_o[nt] = __builtin_amdgcn_mfma_f32_16x16x32_bf16(vf0, pf0, acc_o[nt], 0, 0, 0);
            acc_o[nt] = __builtin_amdgcn_mfma_f32_16x16x32_bf16(vf1, pf1, acc_o[nt], 0, 0, 0);
        }
    }

    float lall = __shfl(acc_l[0], l15);
    float inv  = 1.f / lall;
    size_t trow = (size_t)(b * TB) + q0 + w * 16 + l15;
    #pragma unroll
    for (int nt = 0; nt < 4; nt++) {
        bf16x4 st;
        #pragma unroll
        for (int r = 0; r < 4; r++) st[r] = (__bf16)(acc_o[nt][r] * inv);
        *(bf16x4*)&O[trow * CC + h * HD + nt * 16 + quad * 4] = st;
    }
}

extern "C" void kernel_launch(void* const* d_in, const int* in_sizes, int n_in,
                              void* d_out, int out_size, void* d_ws, size_t ws_size,
                              hipStream_t stream) {
    (void)in_sizes; (void)n_in; (void)out_size; (void)ws_size;
    const float* hidden   = (const float*)d_in[0];
    const float* W_attn   = (const float*)d_in[1];
    const float* b_attn   = (const float*)d_in[2];
    const float* W_proj   = (const float*)d_in[3];
    const float* b_proj   = (const float*)d_in[4];
    const float* kv_scale = (const float*)d_in[5];
    const float* kv_zp    = (const float*)d_in[6];
    float* out = (float*)d_out;

    __bf16* hb  = (__bf16*)d_ws;
    __bf16* wat = hb  + (size_t)4096 * 1024;
    __bf16* wpt = wat + (size_t)3072 * 1024;
    __bf16* qws = wpt + (size_t)1024 * 1024;
    __bf16* kws = qws + (size_t)2 * NH * TB * HD;
    __bf16* vws = kws + (size_t)2 * NH * TB * HD;
    __bf16* ows = vws + (size_t)2 * NH * TB * HD;

    cvt_kernel<<<4096, 256, 0, stream>>>(hidden, hb);
    tpose_kernel<<<dim3(48, 16), 256, 0, stream>>>(W_attn, wat, 1024, 3072);
    tpose_kernel<<<dim3(16, 16), 256, 0, stream>>>(W_proj, wpt, 1024, 1024);

    gemm_bt<128, 0><<<dim3(24, 32), 256, 0, stream>>>(
        hb, wat, b_attn, qws, kws, vws, nullptr, 4096, 3072, 1024, kv_scale, kv_zp);

    attn_mfma<<<dim3(32 * 32), 256, 0, stream>>>(qws, kws, vws, ows);

    gemm_bt<64, 1><<<dim3(16, 32), 256, 0, stream>>>(
        ows, wpt, b_proj, nullptr, nullptr, nullptr, out, 4096, 1024, 1024,
        kv_scale, kv_zp);
}

// Round 6
// 182.271 us; speedup vs baseline: 1.0642x; 1.0642x over previous
//
#include <hip/hip_runtime.h>
#include <math.h>

#define TB 2048
#define CC 1024
#define NH 16
#define HD 64

typedef __bf16 bf16x8 __attribute__((ext_vector_type(8)));
typedef __bf16 bf16x4 __attribute__((ext_vector_type(4)));
typedef float  f32x4  __attribute__((ext_vector_type(4)));

__device__ inline float exp2fast(float x) { return __builtin_amdgcn_exp2f(x); }

// async global->LDS, 16B per lane; LDS dest = wave-uniform base + lane*16
__device__ __forceinline__ void gl_lds16(const __bf16* g, __bf16* l) {
    __builtin_amdgcn_global_load_lds(
        (const __attribute__((address_space(1))) void*)g,
        (__attribute__((address_space(3))) void*)l, 16, 0, 0);
}

// ---------------------------------------------------------------------------
// Fused prep: blocks [0,4096) cvt hidden fp32->bf16; [4096,4864) transpose
// W_attn [1024][3072] -> bf16 [3072][1024]; [4864,5120) transpose W_proj.
// ---------------------------------------------------------------------------
__global__ __launch_bounds__(256)
void prep_kernel(const float* __restrict__ hidden, __bf16* __restrict__ hb,
                 const float* __restrict__ Wa, __bf16* __restrict__ wat,
                 const float* __restrict__ Wp, __bf16* __restrict__ wpt)
{
    __shared__ __bf16 L[64][68];
    const int tid = threadIdx.x;
    const int bid = blockIdx.x;
    if (bid < 4096) {
        int i = (bid * 256 + tid) * 4;
        f32x4 v = *(const f32x4*)&hidden[i];
        bf16x4 o;
        o.x = (__bf16)v.x; o.y = (__bf16)v.y; o.z = (__bf16)v.z; o.w = (__bf16)v.w;
        *(bf16x4*)&hb[i] = o;
        return;
    }
    const float* src; __bf16* dst; int N, n0, k0;
    if (bid < 4096 + 768) {
        int t = bid - 4096;
        src = Wa; dst = wat; N = 3072;
        n0 = (t % 48) * 64; k0 = (t / 48) * 64;
    } else {
        int t = bid - 4864;
        src = Wp; dst = wpt; N = 1024;
        n0 = (t % 16) * 64; k0 = (t / 16) * 64;
    }
    #pragma unroll
    for (int i = 0; i < 4; i++) {
        int id = tid + i * 256;
        int r = id >> 4, c = (id & 15) * 4;
        f32x4 v = *(const f32x4*)&src[(size_t)(k0 + r) * N + n0 + c];
        bf16x4 o;
        o.x = (__bf16)v.x; o.y = (__bf16)v.y; o.z = (__bf16)v.z; o.w = (__bf16)v.w;
        *(bf16x4*)&L[r][c] = o;
    }
    __syncthreads();
    #pragma unroll
    for (int i = 0; i < 4; i++) {
        int id = tid + i * 256;
        int nr = id >> 4, kc = (id & 15) * 4;
        bf16x4 o;
        o.x = L[kc + 0][nr]; o.y = L[kc + 1][nr];
        o.z = L[kc + 2][nr]; o.w = L[kc + 3][nr];
        *(bf16x4*)&dst[(size_t)(n0 + nr) * 1024 + k0 + kc] = o;
    }
}

// ---------------------------------------------------------------------------
// bf16 GEMM, B pre-transposed [N][K]. Tile 128 x BN, BK=64 (half the barrier
// drains of BK=32 at K=1024). 3-bit XOR swizzle: 16B segment s of row r holds
// global segment s^(r&7) -> b128 frag reads conflict-free on the 128B rows;
// staging stays 128B-line coalesced. acc = C^T (operands swapped) -> each
// thread owns 4 consecutive n -> vectorized epilogue.
// MODE 0: bias+split+fake-quant -> bf16 q/k/v [B,H,T,D]; Q pre-scaled by
// 0.125*log2(e). MODE 1: bias -> fp32 row-major.
// ---------------------------------------------------------------------------
template<int BN, int MODE>
__global__ __launch_bounds__(256)
void gemm_bt(const __bf16* __restrict__ A, const __bf16* __restrict__ Bt,
             const float* __restrict__ bias,
             __bf16* __restrict__ o0, __bf16* __restrict__ o1,
             __bf16* __restrict__ o2, float* __restrict__ of,
             int M, int N, int K,
             const float* __restrict__ scp, const float* __restrict__ zpp)
{
    constexpr int NT = BN / 32;
    __shared__ __bf16 Asm[128][64];
    __shared__ __bf16 Bsm[BN][64];

    const int tid  = threadIdx.x;
    const int m0   = blockIdx.y * 128;
    const int n0   = blockIdx.x * BN;
    const int w    = tid >> 6, lane = tid & 63;
    const int wm   = (w & 1) * 64, wn = (w >> 1) * (BN / 2);
    const int r16  = lane & 15, quad = lane >> 4;
    // staging: 8 lanes/row; lane fetches global segment (lane&7)^(row&7)
    const int srow = lane >> 3;                    // 0..7 (row within instr)
    const int scol = ((lane & 7) ^ srow) * 8;
    // frag reads: global segment g=ks*4+quad lives at slot g^(r16&7)
    const int rsw  = r16 & 7;

    f32x4 acc[NT][4];
    #pragma unroll
    for (int i = 0; i < NT; i++)
        #pragma unroll
        for (int j = 0; j < 4; j++) acc[i][j] = 0.f;

    for (int k0 = 0; k0 < K; k0 += 64) {
        #pragma unroll
        for (int p = 0; p < 4; p++)
            gl_lds16(&A[(size_t)(m0 + w * 32 + p * 8 + srow) * K + k0 + scol],
                     &Asm[w * 32 + p * 8][0]);
        #pragma unroll
        for (int p = 0; p < BN / 32; p++)
            gl_lds16(&Bt[(size_t)(n0 + w * (BN / 4) + p * 8 + srow) * K + k0 + scol],
                     &Bsm[w * (BN / 4) + p * 8][0]);
        __syncthreads();   // drains vmcnt -> DMA complete

        #pragma unroll
        for (int ks = 0; ks < 2; ks++) {
            const int col = ((ks * 4 + quad) ^ rsw) * 8;
            bf16x8 af[4], bfr[NT];
            #pragma unroll
            for (int mt = 0; mt < 4; mt++)
                af[mt] = *(const bf16x8*)&Asm[wm + mt * 16 + r16][col];
            #pragma unroll
            for (int nt = 0; nt < NT; nt++)
                bfr[nt] = *(const bf16x8*)&Bsm[wn + nt * 16 + r16][col];
            #pragma unroll
            for (int nt = 0; nt < NT; nt++)
                #pragma unroll
                for (int mt = 0; mt < 4; mt++)
                    acc[nt][mt] = __builtin_amdgcn_mfma_f32_16x16x32_bf16(
                        bfr[nt], af[mt], acc[nt][mt], 0, 0, 0);
        }
        __syncthreads();
    }

    const float sc = scp[0];
    const float zp = zpp[0];

    #pragma unroll
    for (int nt = 0; nt < NT; nt++) {
        #pragma unroll
        for (int mt = 0; mt < 4; mt++) {
            int gm = m0 + wm + mt * 16 + r16;           // C row (col of D)
            int gn = n0 + wn + nt * 16 + quad * 4;      // C col base (row of D)
            f32x4 val = acc[nt][mt] + *(const f32x4*)&bias[gn];
            if (MODE == 1) {
                *(f32x4*)&of[(size_t)gm * N + gn] = val;
            } else {
                int part = gn >> 10;
                int idx  = gn & 1023;
                int h = idx >> 6, d = idx & 63;
                int b = gm >> 11, t = gm & 2047;
                size_t off = (((size_t)(b * NH + h)) * TB + t) * HD + d;
                bf16x4 st;
                if (part == 0) {
                    #pragma unroll
                    for (int r = 0; r < 4; r++)
                        st[r] = (__bf16)(val[r] * 0.18033688f);  // 0.125*log2e
                    *(bf16x4*)&o0[off] = st;
                } else {
                    #pragma unroll
                    for (int r = 0; r < 4; r++) {
                        float qv = val[r] / sc + zp;
                        qv = rintf(qv);                 // half-to-even
                        qv = fminf(fmaxf(qv, 0.f), 255.f);
                        st[r] = (__bf16)((qv - zp) * sc);
                    }
                    if (part == 1) *(bf16x4*)&o1[off] = st;
                    else           *(bf16x4*)&o2[off] = st;
                }
            }
        }
    }
}

// ---------------------------------------------------------------------------
// Transposed-S MFMA flash attention (unchanged from round 4/5).
// ---------------------------------------------------------------------------
__global__ __launch_bounds__(256, 4)
void attn_mfma(const __bf16* __restrict__ Q, const __bf16* __restrict__ Kg,
               const __bf16* __restrict__ Vg, __bf16* __restrict__ O)
{
    __shared__ alignas(16) __bf16 Ksm[64][72];   // [key][d]
    __shared__ alignas(16) __bf16 Vsm[64][72];   // [d][key]

    const int tid  = threadIdx.x;
    const int qt   = 31 - (blockIdx.x >> 5);     // heavy q-tiles first
    const int bh   = blockIdx.x & 31;
    const int q0   = qt * 64;
    const int w    = tid >> 6, lane = tid & 63;
    const int l15  = lane & 15, quad = lane >> 4;
    const int b    = bh >> 4, h = bh & 15;

    const int krow = tid >> 3;            // 0..31
    const int kseg = (tid & 7) * 8;
    const int vkey = tid & 63;
    const int vc   = tid >> 6;            // 0..3

    const __bf16* Kbh = Kg + (size_t)bh * TB * HD;
    const __bf16* Vbh = Vg + (size_t)bh * TB * HD;

    const __bf16* Qrow = Q + ((size_t)bh * TB + q0 + w * 16 + l15) * HD;
    bf16x8 qf0 = *(const bf16x8*)&Qrow[quad * 8];
    bf16x8 qf1 = *(const bf16x8*)&Qrow[32 + quad * 8];

    const int rbase = (l15 >> 2) * 8 + (l15 & 3);

    bf16x8 af_l;
    {
        __bf16 v = (l15 == 0) ? (__bf16)1.0f : (__bf16)0.0f;
        #pragma unroll
        for (int j = 0; j < 8; j++) af_l[j] = v;
    }

    f32x4 acc_o[4], acc_l;
    #pragma unroll
    for (int nt = 0; nt < 4; nt++) acc_o[nt] = 0.f;
    acc_l = 0.f;
    float mrun = -3.0e38f;

    bf16x8 kpre0 = *(const bf16x8*)&Kbh[(size_t)krow * HD + kseg];
    bf16x8 kpre1 = *(const bf16x8*)&Kbh[(size_t)(32 + krow) * HD + kseg];
    bf16x8 vpre0 = *(const bf16x8*)&Vbh[(size_t)vkey * HD + vc * 8];
    bf16x8 vpre1 = *(const bf16x8*)&Vbh[(size_t)vkey * HD + (4 + vc) * 8];

    for (int kt = 0; kt <= qt; kt++) {
        __syncthreads();
        *(bf16x8*)&Ksm[krow][kseg]      = kpre0;
        *(bf16x8*)&Ksm[32 + krow][kseg] = kpre1;
        #pragma unroll
        for (int j = 0; j < 8; j++) {
            Vsm[vc * 8 + j][vkey]      = vpre0[j];
            Vsm[32 + vc * 8 + j][vkey] = vpre1[j];
        }
        __syncthreads();

        if (kt < qt) {
            const __bf16* Kn = Kbh + (size_t)(kt + 1) * 64 * HD;
            const __bf16* Vn = Vbh + (size_t)(kt + 1) * 64 * HD;
            kpre0 = *(const bf16x8*)&Kn[(size_t)krow * HD + kseg];
            kpre1 = *(const bf16x8*)&Kn[(size_t)(32 + krow) * HD + kseg];
            vpre0 = *(const bf16x8*)&Vn[(size_t)vkey * HD + vc * 8];
            vpre1 = *(const bf16x8*)&Vn[(size_t)vkey * HD + (4 + vc) * 8];
        }

        const bool diag = (kt == qt);

        f32x4 s[4];
        #pragma unroll
        for (int nt = 0; nt < 4; nt++) s[nt] = 0.f;
        #pragma unroll
        for (int nt = 0; nt < 4; nt++) {
            if (diag && (nt & 1) && w < 2) continue;   // keys>=32 all masked
            int row = rbase + (nt & 1) * 32 + ((nt >> 1) << 2);
            bf16x8 kf0 = *(const bf16x8*)&Ksm[row][quad * 8];
            bf16x8 kf1 = *(const bf16x8*)&Ksm[row][32 + quad * 8];
            s[nt] = __builtin_amdgcn_mfma_f32_16x16x32_bf16(kf0, qf0, s[nt], 0, 0, 0);
            s[nt] = __builtin_amdgcn_mfma_f32_16x16x32_bf16(kf1, qf1, s[nt], 0, 0, 0);
        }

        if (diag) {
            #pragma unroll
            for (int nt = 0; nt < 4; nt++) {
                int koff = (nt & 1) * 32 + ((nt >> 1) << 2) + quad * 8;
                #pragma unroll
                for (int r = 0; r < 4; r++)
                    if (koff + r > w * 16 + l15) s[nt][r] = -3.0e38f;
            }
        }

        float mx = s[0][0];
        #pragma unroll
        for (int nt = 0; nt < 4; nt++)
            #pragma unroll
            for (int r = 0; r < 4; r++) mx = fmaxf(mx, s[nt][r]);
        mx = fmaxf(mx, __shfl_xor(mx, 16));
        mx = fmaxf(mx, __shfl_xor(mx, 32));

        float mnew  = fmaxf(mrun, mx);
        float alpha = exp2fast(mrun - mnew);
        mrun = mnew;
        #pragma unroll
        for (int nt = 0; nt < 4; nt++)
            #pragma unroll
            for (int r = 0; r < 4; r++) acc_o[nt][r] *= alpha;
        acc_l[0] *= alpha;

        float p[4][4];
        #pragma unroll
        for (int nt = 0; nt < 4; nt++)
            #pragma unroll
            for (int r = 0; r < 4; r++) p[nt][r] = exp2fast(s[nt][r] - mnew);

        bf16x8 pf0, pf1;
        #pragma unroll
        for (int j = 0; j < 4; j++) {
            pf0[j]     = (__bf16)p[0][j];
            pf0[4 + j] = (__bf16)p[2][j];
            pf1[j]     = (__bf16)p[1][j];
            pf1[4 + j] = (__bf16)p[3][j];
        }

        acc_l = __builtin_amdgcn_mfma_f32_16x16x32_bf16(af_l, pf0, acc_l, 0, 0, 0);
        acc_l = __builtin_amdgcn_mfma_f32_16x16x32_bf16(af_l, pf1, acc_l, 0, 0, 0);

        #pragma unroll
        for (int nt = 0; nt < 4; nt++) {
            bf16x8 vf0 = *(const bf16x8*)&Vsm[nt * 16 + l15][quad * 8];
            bf16x8 vf1 = *(const bf16x8*)&Vsm[nt * 16 + l15][32 + quad * 8];
            acc_o[nt] = __builtin_amdgcn_mfma_f32_16x16x32_bf16(vf0, pf0, acc_o[nt], 0, 0, 0);
            acc_o[nt] = __builtin_amdgcn_mfma_f32_16x16x32_bf16(vf1, pf1, acc_o[nt], 0, 0, 0);
        }
    }

    float lall = __shfl(acc_l[0], l15);
    float inv  = 1.f / lall;
    size_t trow = (size_t)(b * TB) + q0 + w * 16 + l15;
    #pragma unroll
    for (int nt = 0; nt < 4; nt++) {
        bf16x4 st;
        #pragma unroll
        for (int r = 0; r < 4; r++) st[r] = (__bf16)(acc_o[nt][r] * inv);
        *(bf16x4*)&O[trow * CC + h * HD + nt * 16 + quad * 4] = st;
    }
}

extern "C" void kernel_launch(void* const* d_in, const int* in_sizes, int n_in,
                              void* d_out, int out_size, void* d_ws, size_t ws_size,
                              hipStream_t stream) {
    (void)in_sizes; (void)n_in; (void)out_size; (void)ws_size;
    const float* hidden   = (const float*)d_in[0];
    const float* W_attn   = (const float*)d_in[1];
    const float* b_attn   = (const float*)d_in[2];
    const float* W_proj   = (const float*)d_in[3];
    const float* b_proj   = (const float*)d_in[4];
    const float* kv_scale = (const float*)d_in[5];
    const float* kv_zp    = (const float*)d_in[6];
    float* out = (float*)d_out;

    __bf16* hb  = (__bf16*)d_ws;
    __bf16* wat = hb  + (size_t)4096 * 1024;
    __bf16* wpt = wat + (size_t)3072 * 1024;
    __bf16* qws = wpt + (size_t)1024 * 1024;
    __bf16* kws = qws + (size_t)2 * NH * TB * HD;
    __bf16* vws = kws + (size_t)2 * NH * TB * HD;
    __bf16* ows = vws + (size_t)2 * NH * TB * HD;

    prep_kernel<<<5120, 256, 0, stream>>>(hidden, hb, W_attn, wat, W_proj, wpt);

    gemm_bt<128, 0><<<dim3(24, 32), 256, 0, stream>>>(
        hb, wat, b_attn, qws, kws, vws, nullptr, 4096, 3072, 1024, kv_scale, kv_zp);

    attn_mfma<<<dim3(32 * 32), 256, 0, stream>>>(qws, kws, vws, ows);

    gemm_bt<64, 1><<<dim3(16, 32), 256, 0, stream>>>(
        ows, wpt, b_proj, nullptr, nullptr, nullptr, out, 4096, 1024, 1024,
        kv_scale, kv_zp);
}